// Round 2
// baseline (826.736 us; speedup 1.0000x reference)
//
#include <hip/hip_runtime.h>

// Swin shifted-window attention, fused. B=4, C=192, H=W=256, ws=8, shift=4,
// heads=8, hd=24, N=64. 1 block = 1 window, 512 threads = 8 waves.
// v3: split the output path. The fused kernel writes proj+residual (fp32) to a
// window-blocked contiguous buffer Y[win][192][64] in d_ws (full-line 64B
// stores, no write-allocate amplification); a small epilogue kernel unshifts
// Y -> out(B,C,H,W) with coalesced reads/writes. Falls back to direct stores
// if ws_size is too small.
// v2 carry-over: LDS diet (81,552 B) for 2 blocks/CU; K->Q->O region
// time-multiplex; P aliases V; rpb/qkv_b staged bf16.
//
// MFMA 16x16x32 bf16 layouts (learn_hip-verified):
//   A-frag: lane holds A[m=lane&15][k=(lane>>4)*8 + j]
//   B-frag: lane holds B[k=(lane>>4)*8 + j][n=lane&15]
//   C/D   : lane holds D[row=(lane>>4)*4 + r][col=lane&15]

typedef short short8 __attribute__((ext_vector_type(8)));
typedef float f32x4 __attribute__((ext_vector_type(4)));
typedef unsigned short us4 __attribute__((ext_vector_type(4)));

// LDS layout (offsets in 16-bit units)
#define XB_OFF   0        // [12288] x bf16, fragment-swizzled; residual source
#define KQ_OFF   12288    // [12288] K (1a) then Q (1b), per-head swz; then O (2b), X-style swz
#define VT_OFF   24576    // [192][72] V channel-major
#define PB_OFF   24576    // P tiles alias V (V is in registers after 2a)
#define RPB_OFF  38400    // bf16 [8][225] rpb head-major
#define QB_OFF   40200    // bf16 qkv_b [576]
#define LDS_BYTES 81552   // 40776 shorts; 2 blocks/CU (2x80KiB granule = 160KiB)

#define WBF_BYTES 294912u
#define Y_FLOATS_PER_WIN 12288        // 192*64
#define Y_BYTES (4096ull * 49152ull)  // 201,326,592
#define WS_NEED (WBF_BYTES + Y_BYTES)

__device__ __forceinline__ unsigned short f2bfu(float f) {
  union { float f; unsigned u; } v; v.f = f;
  unsigned u = v.u;
  u += 0x7fffu + ((u >> 16) & 1u);   // round-to-nearest-even
  return (unsigned short)(u >> 16);
}
__device__ __forceinline__ float bfu2f(unsigned short s) {
  union { unsigned u; float f; } v; v.u = ((unsigned)s) << 16;
  return v.f;
}

// X/O fragment swizzle: element (token t, channel c) -> short index.
// Matches B-frag load *(short8*)(base + ((tt*6+kk)*64 + lane)*8).
__device__ __forceinline__ int swzX(int t, int c) {
  return (((t >> 4) * 6 + (c >> 5)) << 9) | (((c >> 3) & 3) << 7) |
         ((t & 15) << 3) | (c & 7);
}
// K/Q per-head swizzle: (token-tile i, head h, 8-chan group g, token n, chan j)
// holds X[token = i*16+n][chan = h*24 + g*8 + j]
__device__ __forceinline__ int swzH(int i, int h, int g, int n, int j) {
  return (((i * 8 + h) * 3 + g) << 7) | (n << 3) | j;
}

// -------- prologue: qkv_w/proj_w -> bf16, fragment-swizzled into ws --------
__global__ void prep_weights(const float* __restrict__ qkv_w,
                             const float* __restrict__ proj_w,
                             unsigned short* __restrict__ wbf) {
  int d = blockIdx.x * 512 + threadIdx.x;     // 0..147455
  int j    = d & 7;
  int lane = (d >> 3) & 63;
  int kk   = (d >> 9) % 6;
  int tile = d / 3072;
  int n16 = lane & 15, q4 = lane >> 4;
  int col = kk * 32 + q4 * 8 + j;
  float v = (tile < 36) ? qkv_w[(tile * 16 + n16) * 192 + col]
                        : proj_w[((tile - 36) * 16 + n16) * 192 + col];
  wbf[d] = f2bfu(v);
}

template <bool TOY>
__global__ __launch_bounds__(512, 4) void winattn_kernel(
    const float* __restrict__ x, const float* __restrict__ qkv_b,
    const float* __restrict__ proj_b, const float* __restrict__ rpb,
    const unsigned short* __restrict__ wbf, float* __restrict__ dst)
{
  extern __shared__ __align__(16) char smem[];
  unsigned short* lds = (unsigned short*)smem;

  const int tid  = threadIdx.x;
  const int lane = tid & 63;
  const int wave = tid >> 6;      // 0..7
  const int n16  = lane & 15;
  const int q4   = lane >> 4;

  // XCD-aware swizzle: xcd = blk & 7 heuristic; contiguous window runs per XCD.
  const int blk = blockIdx.x;
  const int L   = (blk & 7) * 512 + (blk >> 3);   // 0..4095 logical
  const int b    = L >> 10;
  const int wIdx = L & 1023;
  const int wr   = wIdx >> 5;
  const int wc   = wIdx & 31;

  // ---------------- phase 0: stage x (bf16, swizzled), rpb, qkv bias ----------------
  {
    const int trow = wave;               // token row 0..7
    const int c3 = lane >> 3, w3 = lane & 7;
    const int hh  = (wr * 8 + 4 + trow) & 255;
    const int ww  = (wc * 8 + 4 + w3) & 255;
    const int t   = trow * 8 + w3;
    #pragma unroll
    for (int it = 0; it < 12; it++) {
      const int c = it * 16 + c3 * 2;
      const float* xp = x + (((size_t)(b * 192 + c)) << 16) + (hh << 8) + ww;
      float v0 = xp[0];
      float v1 = xp[65536];
      unsigned pk = (unsigned)f2bfu(v0) | ((unsigned)f2bfu(v1) << 16);
      *(unsigned*)(lds + XB_OFF + swzX(t, c)) = pk;   // c even -> 4B aligned
    }
    for (int i = tid; i < 1800; i += 512)
      lds[RPB_OFF + (i & 7) * 225 + (i >> 3)] = f2bfu(rpb[i]);  // [h][idx]
    for (int i = tid; i < 576; i += 512)
      lds[QB_OFF + i] = f2bfu(qkv_b[i]);
  }
  __syncthreads();

  // ---------------- phase 1a: K,V = Wkv(384x192) @ X^T (wbf tiles 12..35) ----------------
  {
    short8 bx[4][6];
    #pragma unroll
    for (int tt = 0; tt < 4; tt++)
      #pragma unroll
      for (int kk = 0; kk < 6; kk++)
        bx[tt][kk] = *(const short8*)(lds + XB_OFF + ((tt * 6 + kk) * 64 + lane) * 8);

    #pragma unroll 1
    for (int ot = wave; ot < 24; ot += 8) {
      f32x4 acc[4] = {{0,0,0,0},{0,0,0,0},{0,0,0,0},{0,0,0,0}};
      #pragma unroll
      for (int kk = 0; kk < 6; kk++) {
        short8 af = *(const short8*)(wbf + ((ot + 12) * 6 + kk) * 512 + lane * 8);
        #pragma unroll
        for (int tt = 0; tt < 4; tt++)
          acc[tt] = __builtin_amdgcn_mfma_f32_16x16x32_bf16(af, bx[tt][kk], acc[tt], 0, 0, 0);
      }
      const int ob = (ot + 12) * 16 + q4 * 4;
      const float b0 = bfu2f(lds[QB_OFF + ob + 0]);
      const float b1 = bfu2f(lds[QB_OFF + ob + 1]);
      const float b2 = bfu2f(lds[QB_OFF + ob + 2]);
      const float b3 = bfu2f(lds[QB_OFF + ob + 3]);
      if (ot < 12) {
        const int kc = ot * 16 + q4 * 4;
        const int hk = kc / 24, g = (kc >> 3) % 3, j0 = kc & 7;
        #pragma unroll
        for (int tt = 0; tt < 4; tt++) {
          us4 hv = { f2bfu(acc[tt][0] + b0), f2bfu(acc[tt][1] + b1),
                     f2bfu(acc[tt][2] + b2), f2bfu(acc[tt][3] + b3) };
          *(us4*)(lds + KQ_OFF + swzH(tt, hk, g, n16, j0)) = hv;
        }
      } else {
        const int vc = (ot - 12) * 16 + q4 * 4;
        #pragma unroll
        for (int tt = 0; tt < 4; tt++) {
          const int t = tt * 16 + n16;
          lds[VT_OFF + (vc + 0) * 72 + t] = f2bfu(acc[tt][0] + b0);
          lds[VT_OFF + (vc + 1) * 72 + t] = f2bfu(acc[tt][1] + b1);
          lds[VT_OFF + (vc + 2) * 72 + t] = f2bfu(acc[tt][2] + b2);
          lds[VT_OFF + (vc + 3) * 72 + t] = f2bfu(acc[tt][3] + b3);
        }
      }
    }
  }
  __syncthreads();

  // ---------------- phase 2a: snapshot K/V fragments (wave = head) ----------------
  const int h = wave;
  const short8 zero8 = {0,0,0,0,0,0,0,0};
  short8 kb[4], vb[2][2];
  {
    #pragma unroll
    for (int i = 0; i < 4; i++)
      kb[i] = (q4 < 3) ? *(const short8*)(lds + KQ_OFF + swzH(i, h, q4, n16, 0))
                       : zero8;
    #pragma unroll
    for (int nc = 0; nc < 2; nc++)
      #pragma unroll
      for (int kk = 0; kk < 2; kk++)
        vb[nc][kk] = (nc * 16 + n16 < 24)
          ? *(const short8*)(lds + VT_OFF + (h * 24 + nc * 16 + n16) * 72 + kk * 32 + q4 * 8)
          : zero8;
  }
  __syncthreads();   // all K/V reads done; KQ region free for Q

  // ---------------- phase 1b: Q = Wq(192x192) @ X^T (wbf tiles 0..11) ----------------
  {
    #pragma unroll 1
    for (int ot = wave; ot < 12; ot += 8) {
      f32x4 acc[4] = {{0,0,0,0},{0,0,0,0},{0,0,0,0},{0,0,0,0}};
      #pragma unroll
      for (int kk = 0; kk < 6; kk++) {
        short8 af = *(const short8*)(wbf + (ot * 6 + kk) * 512 + lane * 8);
        #pragma unroll
        for (int tt = 0; tt < 4; tt++) {
          short8 bxk = *(const short8*)(lds + XB_OFF + ((tt * 6 + kk) * 64 + lane) * 8);
          acc[tt] = __builtin_amdgcn_mfma_f32_16x16x32_bf16(af, bxk, acc[tt], 0, 0, 0);
        }
      }
      const int ob = ot * 16 + q4 * 4;
      const float b0 = bfu2f(lds[QB_OFF + ob + 0]);
      const float b1 = bfu2f(lds[QB_OFF + ob + 1]);
      const float b2 = bfu2f(lds[QB_OFF + ob + 2]);
      const float b3 = bfu2f(lds[QB_OFF + ob + 3]);
      const int qc = ot * 16 + q4 * 4;
      const int hq = qc / 24, g = (qc >> 3) % 3, j0 = qc & 7;
      #pragma unroll
      for (int tt = 0; tt < 4; tt++) {
        us4 hv = { f2bfu(acc[tt][0] + b0), f2bfu(acc[tt][1] + b1),
                   f2bfu(acc[tt][2] + b2), f2bfu(acc[tt][3] + b3) };
        *(us4*)(lds + KQ_OFF + swzH(tt, hq, g, n16, j0)) = hv;
      }
    }
  }
  __syncthreads();

  // ---------------- phase 2a': Q frags + S = QK^T ----------------
  f32x4 s[4][4];
  {
    short8 qa[4];
    #pragma unroll
    for (int i = 0; i < 4; i++)
      qa[i] = (q4 < 3) ? *(const short8*)(lds + KQ_OFF + swzH(i, h, q4, n16, 0))
                       : zero8;
    __syncthreads();   // all Q reads done; KQ region free for O
    #pragma unroll
    for (int mi = 0; mi < 4; mi++)
      #pragma unroll
      for (int nj = 0; nj < 4; nj++) {
        f32x4 z = {0,0,0,0};
        s[mi][nj] = __builtin_amdgcn_mfma_f32_16x16x32_bf16(qa[mi], kb[nj], z, 0, 0, 0);
      }
  }

  // ---------------- phase 2b: softmax + PV, streamed per 16-row tile ----------------
  {
    const float scale = 0.20412414523193154f;   // 24^-0.5
    unsigned short* Pw = lds + PB_OFF + wave * 1152;   // [16][72], aliases V
    const unsigned short* rh = lds + RPB_OFF + h * 225;
    int cr[4], cc[4], clab[4];
    #pragma unroll
    for (int nj = 0; nj < 4; nj++) {
      int col = nj * 16 + n16;
      cr[nj] = col >> 3; cc[nj] = col & 7;
      int hs = wr * 8 + cr[nj], wsc = wc * 8 + cc[nj];
      int lh = (hs < 248) ? 0 : (hs < 252 ? 1 : 2);
      int lw = (wsc < 248) ? 0 : (wsc < 252 ? 1 : 2);
      clab[nj] = lh * 3 + lw;
    }
    #pragma unroll 1
    for (int mi = 0; mi < 4; mi++) {
      #pragma unroll
      for (int r = 0; r < 4; r++) {
        int row = mi * 16 + q4 * 4 + r;
        int r1 = row >> 3, c1 = row & 7;
        int hs = wr * 8 + r1, wsc = wc * 8 + c1;
        int lh = (hs < 248) ? 0 : (hs < 252 ? 1 : 2);
        int lw = (wsc < 248) ? 0 : (wsc < 252 ? 1 : 2);
        int rlab = lh * 3 + lw;
        float vals[4];
        float mx = -1e30f;
        #pragma unroll
        for (int nj = 0; nj < 4; nj++) {
          float v = s[mi][nj][r] * scale
                  + bfu2f(rh[(r1 - cr[nj] + 7) * 15 + (c1 - cc[nj] + 7)])
                  + ((rlab == clab[nj]) ? 0.0f : -100.0f);
          vals[nj] = v;
          mx = fmaxf(mx, v);
        }
        mx = fmaxf(mx, __shfl_xor(mx, 1));
        mx = fmaxf(mx, __shfl_xor(mx, 2));
        mx = fmaxf(mx, __shfl_xor(mx, 4));
        mx = fmaxf(mx, __shfl_xor(mx, 8));
        float sum = 0.f;
        #pragma unroll
        for (int nj = 0; nj < 4; nj++) { float p = __expf(vals[nj] - mx); vals[nj] = p; sum += p; }
        sum += __shfl_xor(sum, 1);
        sum += __shfl_xor(sum, 2);
        sum += __shfl_xor(sum, 4);
        sum += __shfl_xor(sum, 8);
        float inv = 1.0f / sum;
        #pragma unroll
        for (int nj = 0; nj < 4; nj++)
          Pw[(q4 * 4 + r) * 72 + nj * 16 + n16] = f2bfu(vals[nj] * inv);
      }
      short8 pa0 = *(const short8*)(Pw + n16 * 72 + q4 * 8);
      short8 pa1 = *(const short8*)(Pw + n16 * 72 + 32 + q4 * 8);
      #pragma unroll
      for (int nc = 0; nc < 2; nc++) {
        f32x4 a = {0,0,0,0};
        a = __builtin_amdgcn_mfma_f32_16x16x32_bf16(pa0, vb[nc][0], a, 0, 0, 0);
        a = __builtin_amdgcn_mfma_f32_16x16x32_bf16(pa1, vb[nc][1], a, 0, 0, 0);
        const int ch = nc * 16 + n16;
        if (ch < 24) {
          const int c = h * 24 + ch;
          #pragma unroll
          for (int r = 0; r < 4; r++) {
            const int t = mi * 16 + q4 * 4 + r;
            lds[KQ_OFF + swzX(t, c)] = f2bfu(a[r]);   // O, X-style swz
          }
        }
      }
    }
  }
  __syncthreads();

  // ---------------- phase 3: proj^T = Wp(192x192) @ O^T, + residual ----------------
  {
    short8 bo[4][6];
    #pragma unroll
    for (int tt = 0; tt < 4; tt++)
      #pragma unroll
      for (int kk = 0; kk < 6; kk++)
        bo[tt][kk] = *(const short8*)(lds + KQ_OFF + ((tt * 6 + kk) * 64 + lane) * 8);

    #pragma unroll 1
    for (int ot = wave; ot < 12; ot += 8) {
      f32x4 acc[4] = {{0,0,0,0},{0,0,0,0},{0,0,0,0},{0,0,0,0}};
      #pragma unroll
      for (int kk = 0; kk < 6; kk++) {
        short8 af = *(const short8*)(wbf + ((36 + ot) * 6 + kk) * 512 + lane * 8);
        #pragma unroll
        for (int tt = 0; tt < 4; tt++)
          acc[tt] = __builtin_amdgcn_mfma_f32_16x16x32_bf16(af, bo[tt][kk], acc[tt], 0, 0, 0);
      }
      if constexpr (TOY) {
        // contiguous window-blocked store: Y[win][o][t], full 64B lines
        float* yw = dst + (size_t)L * Y_FLOATS_PER_WIN;
        #pragma unroll
        for (int r = 0; r < 4; r++) {
          const int o = ot * 16 + q4 * 4 + r;
          const float pb = proj_b[o];
          #pragma unroll
          for (int tt = 0; tt < 4; tt++) {
            const int t = tt * 16 + n16;
            yw[o * 64 + t] = bfu2f(lds[XB_OFF + swzX(t, o)]) + acc[tt][r] + pb;
          }
        }
      } else {
        #pragma unroll
        for (int r = 0; r < 4; r++) {
          const int o = ot * 16 + q4 * 4 + r;
          const float pb = proj_b[o];
          const size_t cbase = ((size_t)(b * 192 + o)) << 16;
          #pragma unroll
          for (int tt = 0; tt < 4; tt++) {
            const int t = tt * 16 + n16;
            const int hh = (wr * 8 + (t >> 3) + 4) & 255;
            const int ww = (wc * 8 + (t & 7) + 4) & 255;
            dst[cbase + (hh << 8) + ww] = bfu2f(lds[XB_OFF + swzX(t, o)]) + acc[tt][r] + pb;
          }
        }
      }
    }
  }
}

// -------- epilogue: Y[win][c][t] (window-blocked, shifted space) -> out(B,C,H,W) --------
// out(c, h, w) = Y[win(b, (h-4)>>3, (w-4)>>3)][c][((h-4)&7)*8 + ((w-4)&7)]
// Block = (b, wr, cg of 24 channels); reads 32B-aligned segments with full
// block-local line reuse; writes contiguous rotated rows.
__global__ __launch_bounds__(512) void unshift_kernel(
    const float* __restrict__ Y, float* __restrict__ out)
{
  const int bid = blockIdx.x;
  const int cg = bid & 7;           // 8 channel groups x 24
  const int wr = (bid >> 3) & 31;
  const int b  = bid >> 8;
  const size_t winrow = ((size_t)(b * 32 + wr)) * 32;   // first window of this row-band

  for (int i = threadIdx.x; i < 24 * 2048; i += 512) {
    const int c_rel = i >> 11;          // 0..23
    const int rem   = i & 2047;
    const int trow  = rem >> 8;         // 0..7
    const int wp    = rem & 255;        // shifted col 0..255
    const int c     = cg * 24 + c_rel;
    const float v = Y[(winrow + (wp >> 3)) * Y_FLOATS_PER_WIN + c * 64 + trow * 8 + (wp & 7)];
    const int hh = (wr * 8 + trow + 4) & 255;
    const int ww = (wp + 4) & 255;
    out[(((size_t)(b * 192 + c)) << 16) + (hh << 8) + ww] = v;
  }
}

extern "C" void kernel_launch(void* const* d_in, const int* in_sizes, int n_in,
                              void* d_out, int out_size, void* d_ws, size_t ws_size,
                              hipStream_t stream) {
  const float* x      = (const float*)d_in[0];
  const float* qkv_w  = (const float*)d_in[1];
  const float* qkv_b  = (const float*)d_in[2];
  const float* proj_w = (const float*)d_in[3];
  const float* proj_b = (const float*)d_in[4];
  const float* rpb    = (const float*)d_in[5];
  float* out = (float*)d_out;
  unsigned short* wbf = (unsigned short*)d_ws;    // 147456 shorts = 294912 B

  hipFuncSetAttribute(reinterpret_cast<const void*>(&winattn_kernel<true>),
                      hipFuncAttributeMaxDynamicSharedMemorySize, LDS_BYTES);
  hipFuncSetAttribute(reinterpret_cast<const void*>(&winattn_kernel<false>),
                      hipFuncAttributeMaxDynamicSharedMemorySize, LDS_BYTES);

  prep_weights<<<dim3(288), dim3(512), 0, stream>>>(qkv_w, proj_w, wbf);

  if (ws_size >= (size_t)WS_NEED) {
    float* Y = (float*)((char*)d_ws + WBF_BYTES);
    winattn_kernel<true><<<dim3(4096), dim3(512), LDS_BYTES, stream>>>(
        x, qkv_b, proj_b, rpb, wbf, Y);
    unshift_kernel<<<dim3(1024), dim3(512), 0, stream>>>(Y, out);
  } else {
    winattn_kernel<false><<<dim3(4096), dim3(512), LDS_BYTES, stream>>>(
        x, qkv_b, proj_b, rpb, wbf, out);
  }
}

// Round 3
// 651.128 us; speedup vs baseline: 1.2697x; 1.2697x over previous
//
#include <hip/hip_runtime.h>

// Swin shifted-window attention, fused. B=4, C=192, H=W=256, ws=8, shift=4,
// heads=8, hd=24, N=64. 1 block = 1 window, 512 threads = 8 waves.
// v4: kill scratch. v3's `f32x4 s[4][4]` was runtime-indexed by the
// `#pragma unroll 1` mi loop -> 256 B/thread local memory -> ~672 MiB of
// deterministic HBM write traffic (the exact-864-MiB WRITE_SIZE mystery).
// Fix: fuse QK^T into a fully-unrolled mi loop; live S is one row-tile
// (f32x4 smi[4]), every array index static.
// v3 carry-over: window-blocked Y output + unshift epilogue.
// v2 carry-over: LDS diet (81,552 B) for 2 blocks/CU; K->Q->O time-multiplex.
//
// MFMA 16x16x32 bf16 layouts (learn_hip-verified):
//   A-frag: lane holds A[m=lane&15][k=(lane>>4)*8 + j]
//   B-frag: lane holds B[k=(lane>>4)*8 + j][n=lane&15]
//   C/D   : lane holds D[row=(lane>>4)*4 + r][col=lane&15]

typedef short short8 __attribute__((ext_vector_type(8)));
typedef float f32x4 __attribute__((ext_vector_type(4)));
typedef unsigned short us4 __attribute__((ext_vector_type(4)));

// LDS layout (offsets in 16-bit units)
#define XB_OFF   0        // [12288] x bf16, fragment-swizzled; residual source
#define KQ_OFF   12288    // [12288] K (1a) then Q (1b), per-head swz; then O (2b), X-style swz
#define VT_OFF   24576    // [192][72] V channel-major
#define PB_OFF   24576    // P tiles alias V (V is in registers after 2a)
#define RPB_OFF  38400    // bf16 [8][225] rpb head-major
#define QB_OFF   40200    // bf16 qkv_b [576]
#define LDS_BYTES 81552   // 40776 shorts; 2 blocks/CU (2x80KiB granule = 160KiB)

#define WBF_BYTES 294912u
#define Y_FLOATS_PER_WIN 12288        // 192*64
#define Y_BYTES (4096ull * 49152ull)  // 201,326,592
#define WS_NEED (WBF_BYTES + Y_BYTES)

__device__ __forceinline__ unsigned short f2bfu(float f) {
  union { float f; unsigned u; } v; v.f = f;
  unsigned u = v.u;
  u += 0x7fffu + ((u >> 16) & 1u);   // round-to-nearest-even
  return (unsigned short)(u >> 16);
}
__device__ __forceinline__ float bfu2f(unsigned short s) {
  union { unsigned u; float f; } v; v.u = ((unsigned)s) << 16;
  return v.f;
}

// X/O fragment swizzle: element (token t, channel c) -> short index.
// Matches B-frag load *(short8*)(base + ((tt*6+kk)*64 + lane)*8).
__device__ __forceinline__ int swzX(int t, int c) {
  return (((t >> 4) * 6 + (c >> 5)) << 9) | (((c >> 3) & 3) << 7) |
         ((t & 15) << 3) | (c & 7);
}
// K/Q per-head swizzle: (token-tile i, head h, 8-chan group g, token n, chan j)
// holds X[token = i*16+n][chan = h*24 + g*8 + j]
__device__ __forceinline__ int swzH(int i, int h, int g, int n, int j) {
  return (((i * 8 + h) * 3 + g) << 7) | (n << 3) | j;
}

// -------- prologue: qkv_w/proj_w -> bf16, fragment-swizzled into ws --------
__global__ void prep_weights(const float* __restrict__ qkv_w,
                             const float* __restrict__ proj_w,
                             unsigned short* __restrict__ wbf) {
  int d = blockIdx.x * 512 + threadIdx.x;     // 0..147455
  int j    = d & 7;
  int lane = (d >> 3) & 63;
  int kk   = (d >> 9) % 6;
  int tile = d / 3072;
  int n16 = lane & 15, q4 = lane >> 4;
  int col = kk * 32 + q4 * 8 + j;
  float v = (tile < 36) ? qkv_w[(tile * 16 + n16) * 192 + col]
                        : proj_w[((tile - 36) * 16 + n16) * 192 + col];
  wbf[d] = f2bfu(v);
}

template <bool TOY>
__global__ __launch_bounds__(512, 4) void winattn_kernel(
    const float* __restrict__ x, const float* __restrict__ qkv_b,
    const float* __restrict__ proj_b, const float* __restrict__ rpb,
    const unsigned short* __restrict__ wbf, float* __restrict__ dst)
{
  extern __shared__ __align__(16) char smem[];
  unsigned short* lds = (unsigned short*)smem;

  const int tid  = threadIdx.x;
  const int lane = tid & 63;
  const int wave = tid >> 6;      // 0..7
  const int n16  = lane & 15;
  const int q4   = lane >> 4;

  // XCD-aware swizzle: xcd = blk & 7 heuristic; contiguous window runs per XCD.
  const int blk = blockIdx.x;
  const int L   = (blk & 7) * 512 + (blk >> 3);   // 0..4095 logical
  const int b    = L >> 10;
  const int wIdx = L & 1023;
  const int wr   = wIdx >> 5;
  const int wc   = wIdx & 31;

  // ---------------- phase 0: stage x (bf16, swizzled), rpb, qkv bias ----------------
  {
    const int trow = wave;               // token row 0..7
    const int c3 = lane >> 3, w3 = lane & 7;
    const int hh  = (wr * 8 + 4 + trow) & 255;
    const int ww  = (wc * 8 + 4 + w3) & 255;
    const int t   = trow * 8 + w3;
    #pragma unroll
    for (int it = 0; it < 12; it++) {
      const int c = it * 16 + c3 * 2;
      const float* xp = x + (((size_t)(b * 192 + c)) << 16) + (hh << 8) + ww;
      float v0 = xp[0];
      float v1 = xp[65536];
      unsigned pk = (unsigned)f2bfu(v0) | ((unsigned)f2bfu(v1) << 16);
      *(unsigned*)(lds + XB_OFF + swzX(t, c)) = pk;   // c even -> 4B aligned
    }
    for (int i = tid; i < 1800; i += 512)
      lds[RPB_OFF + (i & 7) * 225 + (i >> 3)] = f2bfu(rpb[i]);  // [h][idx]
    for (int i = tid; i < 576; i += 512)
      lds[QB_OFF + i] = f2bfu(qkv_b[i]);
  }
  __syncthreads();

  // ---------------- phase 1a: K,V = Wkv(384x192) @ X^T (wbf tiles 12..35) ----------------
  {
    short8 bx[4][6];
    #pragma unroll
    for (int tt = 0; tt < 4; tt++)
      #pragma unroll
      for (int kk = 0; kk < 6; kk++)
        bx[tt][kk] = *(const short8*)(lds + XB_OFF + ((tt * 6 + kk) * 64 + lane) * 8);

    #pragma unroll 1
    for (int ot = wave; ot < 24; ot += 8) {
      f32x4 acc[4] = {{0,0,0,0},{0,0,0,0},{0,0,0,0},{0,0,0,0}};
      #pragma unroll
      for (int kk = 0; kk < 6; kk++) {
        short8 af = *(const short8*)(wbf + ((ot + 12) * 6 + kk) * 512 + lane * 8);
        #pragma unroll
        for (int tt = 0; tt < 4; tt++)
          acc[tt] = __builtin_amdgcn_mfma_f32_16x16x32_bf16(af, bx[tt][kk], acc[tt], 0, 0, 0);
      }
      const int ob = (ot + 12) * 16 + q4 * 4;
      const float b0 = bfu2f(lds[QB_OFF + ob + 0]);
      const float b1 = bfu2f(lds[QB_OFF + ob + 1]);
      const float b2 = bfu2f(lds[QB_OFF + ob + 2]);
      const float b3 = bfu2f(lds[QB_OFF + ob + 3]);
      if (ot < 12) {
        const int kc = ot * 16 + q4 * 4;
        const int hk = kc / 24, g = (kc >> 3) % 3, j0 = kc & 7;
        #pragma unroll
        for (int tt = 0; tt < 4; tt++) {
          us4 hv = { f2bfu(acc[tt][0] + b0), f2bfu(acc[tt][1] + b1),
                     f2bfu(acc[tt][2] + b2), f2bfu(acc[tt][3] + b3) };
          *(us4*)(lds + KQ_OFF + swzH(tt, hk, g, n16, j0)) = hv;
        }
      } else {
        const int vc = (ot - 12) * 16 + q4 * 4;
        #pragma unroll
        for (int tt = 0; tt < 4; tt++) {
          const int t = tt * 16 + n16;
          lds[VT_OFF + (vc + 0) * 72 + t] = f2bfu(acc[tt][0] + b0);
          lds[VT_OFF + (vc + 1) * 72 + t] = f2bfu(acc[tt][1] + b1);
          lds[VT_OFF + (vc + 2) * 72 + t] = f2bfu(acc[tt][2] + b2);
          lds[VT_OFF + (vc + 3) * 72 + t] = f2bfu(acc[tt][3] + b3);
        }
      }
    }
  }
  __syncthreads();

  // ---------------- phase 2a: snapshot K/V fragments (wave = head) ----------------
  const int h = wave;
  const short8 zero8 = {0,0,0,0,0,0,0,0};
  short8 kb[4], vb[2][2];
  {
    #pragma unroll
    for (int i = 0; i < 4; i++)
      kb[i] = (q4 < 3) ? *(const short8*)(lds + KQ_OFF + swzH(i, h, q4, n16, 0))
                       : zero8;
    #pragma unroll
    for (int nc = 0; nc < 2; nc++)
      #pragma unroll
      for (int kk = 0; kk < 2; kk++)
        vb[nc][kk] = (nc * 16 + n16 < 24)
          ? *(const short8*)(lds + VT_OFF + (h * 24 + nc * 16 + n16) * 72 + kk * 32 + q4 * 8)
          : zero8;
  }
  __syncthreads();   // all K/V reads done; KQ region free for Q

  // ---------------- phase 1b: Q = Wq(192x192) @ X^T (wbf tiles 0..11) ----------------
  {
    #pragma unroll 1
    for (int ot = wave; ot < 12; ot += 8) {
      f32x4 acc[4] = {{0,0,0,0},{0,0,0,0},{0,0,0,0},{0,0,0,0}};
      #pragma unroll
      for (int kk = 0; kk < 6; kk++) {
        short8 af = *(const short8*)(wbf + (ot * 6 + kk) * 512 + lane * 8);
        #pragma unroll
        for (int tt = 0; tt < 4; tt++) {
          short8 bxk = *(const short8*)(lds + XB_OFF + ((tt * 6 + kk) * 64 + lane) * 8);
          acc[tt] = __builtin_amdgcn_mfma_f32_16x16x32_bf16(af, bxk, acc[tt], 0, 0, 0);
        }
      }
      const int ob = ot * 16 + q4 * 4;
      const float b0 = bfu2f(lds[QB_OFF + ob + 0]);
      const float b1 = bfu2f(lds[QB_OFF + ob + 1]);
      const float b2 = bfu2f(lds[QB_OFF + ob + 2]);
      const float b3 = bfu2f(lds[QB_OFF + ob + 3]);
      const int qc = ot * 16 + q4 * 4;
      const int hq = qc / 24, g = (qc >> 3) % 3, j0 = qc & 7;
      #pragma unroll
      for (int tt = 0; tt < 4; tt++) {
        us4 hv = { f2bfu(acc[tt][0] + b0), f2bfu(acc[tt][1] + b1),
                   f2bfu(acc[tt][2] + b2), f2bfu(acc[tt][3] + b3) };
        *(us4*)(lds + KQ_OFF + swzH(tt, hq, g, n16, j0)) = hv;
      }
    }
  }
  __syncthreads();

  // ---------------- phase 2: Q frags; fused per-row-tile QK^T + softmax + PV ----------------
  {
    short8 qa[4];
    #pragma unroll
    for (int i = 0; i < 4; i++)
      qa[i] = (q4 < 3) ? *(const short8*)(lds + KQ_OFF + swzH(i, h, q4, n16, 0))
                       : zero8;
    __syncthreads();   // all Q reads done; KQ region free for O

    const float scale = 0.20412414523193154f;   // 24^-0.5
    unsigned short* Pw = lds + PB_OFF + wave * 1152;   // [16][72], aliases V
    const unsigned short* rh = lds + RPB_OFF + h * 225;
    int cr[4], cc[4], clab[4];
    #pragma unroll
    for (int nj = 0; nj < 4; nj++) {
      int col = nj * 16 + n16;
      cr[nj] = col >> 3; cc[nj] = col & 7;
      int hs = wr * 8 + cr[nj], wsc = wc * 8 + cc[nj];
      int lh = (hs < 248) ? 0 : (hs < 252 ? 1 : 2);
      int lw = (wsc < 248) ? 0 : (wsc < 252 ? 1 : 2);
      clab[nj] = lh * 3 + lw;
    }
    // FULLY unrolled: every index into qa/smi/vals is compile-time constant
    // (rule #20 — runtime-indexed ext_vector arrays go to scratch).
    #pragma unroll
    for (int mi = 0; mi < 4; mi++) {
      f32x4 smi[4];
      #pragma unroll
      for (int nj = 0; nj < 4; nj++) {
        f32x4 z = {0,0,0,0};
        smi[nj] = __builtin_amdgcn_mfma_f32_16x16x32_bf16(qa[mi], kb[nj], z, 0, 0, 0);
      }
      #pragma unroll
      for (int r = 0; r < 4; r++) {
        int row = mi * 16 + q4 * 4 + r;
        int r1 = row >> 3, c1 = row & 7;
        int hs = wr * 8 + r1, wsc = wc * 8 + c1;
        int lh = (hs < 248) ? 0 : (hs < 252 ? 1 : 2);
        int lw = (wsc < 248) ? 0 : (wsc < 252 ? 1 : 2);
        int rlab = lh * 3 + lw;
        float vals[4];
        float mx = -1e30f;
        #pragma unroll
        for (int nj = 0; nj < 4; nj++) {
          float v = smi[nj][r] * scale
                  + bfu2f(rh[(r1 - cr[nj] + 7) * 15 + (c1 - cc[nj] + 7)])
                  + ((rlab == clab[nj]) ? 0.0f : -100.0f);
          vals[nj] = v;
          mx = fmaxf(mx, v);
        }
        mx = fmaxf(mx, __shfl_xor(mx, 1));
        mx = fmaxf(mx, __shfl_xor(mx, 2));
        mx = fmaxf(mx, __shfl_xor(mx, 4));
        mx = fmaxf(mx, __shfl_xor(mx, 8));
        float sum = 0.f;
        #pragma unroll
        for (int nj = 0; nj < 4; nj++) { float p = __expf(vals[nj] - mx); vals[nj] = p; sum += p; }
        sum += __shfl_xor(sum, 1);
        sum += __shfl_xor(sum, 2);
        sum += __shfl_xor(sum, 4);
        sum += __shfl_xor(sum, 8);
        float inv = 1.0f / sum;
        #pragma unroll
        for (int nj = 0; nj < 4; nj++)
          Pw[(q4 * 4 + r) * 72 + nj * 16 + n16] = f2bfu(vals[nj] * inv);
      }
      short8 pa0 = *(const short8*)(Pw + n16 * 72 + q4 * 8);
      short8 pa1 = *(const short8*)(Pw + n16 * 72 + 32 + q4 * 8);
      #pragma unroll
      for (int nc = 0; nc < 2; nc++) {
        f32x4 a = {0,0,0,0};
        a = __builtin_amdgcn_mfma_f32_16x16x32_bf16(pa0, vb[nc][0], a, 0, 0, 0);
        a = __builtin_amdgcn_mfma_f32_16x16x32_bf16(pa1, vb[nc][1], a, 0, 0, 0);
        const int ch = nc * 16 + n16;
        if (ch < 24) {
          const int c = h * 24 + ch;
          #pragma unroll
          for (int r = 0; r < 4; r++) {
            const int t = mi * 16 + q4 * 4 + r;
            lds[KQ_OFF + swzX(t, c)] = f2bfu(a[r]);   // O, X-style swz
          }
        }
      }
    }
  }
  __syncthreads();

  // ---------------- phase 3: proj^T = Wp(192x192) @ O^T, + residual ----------------
  {
    short8 bo[4][6];
    #pragma unroll
    for (int tt = 0; tt < 4; tt++)
      #pragma unroll
      for (int kk = 0; kk < 6; kk++)
        bo[tt][kk] = *(const short8*)(lds + KQ_OFF + ((tt * 6 + kk) * 64 + lane) * 8);

    #pragma unroll 1
    for (int ot = wave; ot < 12; ot += 8) {
      f32x4 acc[4] = {{0,0,0,0},{0,0,0,0},{0,0,0,0},{0,0,0,0}};
      #pragma unroll
      for (int kk = 0; kk < 6; kk++) {
        short8 af = *(const short8*)(wbf + ((36 + ot) * 6 + kk) * 512 + lane * 8);
        #pragma unroll
        for (int tt = 0; tt < 4; tt++)
          acc[tt] = __builtin_amdgcn_mfma_f32_16x16x32_bf16(af, bo[tt][kk], acc[tt], 0, 0, 0);
      }
      if constexpr (TOY) {
        // contiguous window-blocked store: Y[win][o][t], full 64B lines
        float* yw = dst + (size_t)L * Y_FLOATS_PER_WIN;
        #pragma unroll
        for (int r = 0; r < 4; r++) {
          const int o = ot * 16 + q4 * 4 + r;
          const float pb = proj_b[o];
          #pragma unroll
          for (int tt = 0; tt < 4; tt++) {
            const int t = tt * 16 + n16;
            yw[o * 64 + t] = bfu2f(lds[XB_OFF + swzX(t, o)]) + acc[tt][r] + pb;
          }
        }
      } else {
        #pragma unroll
        for (int r = 0; r < 4; r++) {
          const int o = ot * 16 + q4 * 4 + r;
          const float pb = proj_b[o];
          const size_t cbase = ((size_t)(b * 192 + o)) << 16;
          #pragma unroll
          for (int tt = 0; tt < 4; tt++) {
            const int t = tt * 16 + n16;
            const int hh = (wr * 8 + (t >> 3) + 4) & 255;
            const int ww = (wc * 8 + (t & 7) + 4) & 255;
            dst[cbase + (hh << 8) + ww] = bfu2f(lds[XB_OFF + swzX(t, o)]) + acc[tt][r] + pb;
          }
        }
      }
    }
  }
}

// -------- epilogue: Y[win][c][t] (window-blocked, shifted space) -> out(B,C,H,W) --------
__global__ __launch_bounds__(512) void unshift_kernel(
    const float* __restrict__ Y, float* __restrict__ out)
{
  const int bid = blockIdx.x;
  const int cg = bid & 7;           // 8 channel groups x 24
  const int wr = (bid >> 3) & 31;
  const int b  = bid >> 8;
  const size_t winrow = ((size_t)(b * 32 + wr)) * 32;   // first window of this row-band

  for (int i = threadIdx.x; i < 24 * 2048; i += 512) {
    const int c_rel = i >> 11;          // 0..23
    const int rem   = i & 2047;
    const int trow  = rem >> 8;         // 0..7
    const int wp    = rem & 255;        // shifted col 0..255
    const int c     = cg * 24 + c_rel;
    const float v = Y[(winrow + (wp >> 3)) * Y_FLOATS_PER_WIN + c * 64 + trow * 8 + (wp & 7)];
    const int hh = (wr * 8 + trow + 4) & 255;
    const int ww = (wp + 4) & 255;
    out[(((size_t)(b * 192 + c)) << 16) + (hh << 8) + ww] = v;
  }
}

extern "C" void kernel_launch(void* const* d_in, const int* in_sizes, int n_in,
                              void* d_out, int out_size, void* d_ws, size_t ws_size,
                              hipStream_t stream) {
  const float* x      = (const float*)d_in[0];
  const float* qkv_w  = (const float*)d_in[1];
  const float* qkv_b  = (const float*)d_in[2];
  const float* proj_w = (const float*)d_in[3];
  const float* proj_b = (const float*)d_in[4];
  const float* rpb    = (const float*)d_in[5];
  float* out = (float*)d_out;
  unsigned short* wbf = (unsigned short*)d_ws;    // 147456 shorts = 294912 B

  hipFuncSetAttribute(reinterpret_cast<const void*>(&winattn_kernel<true>),
                      hipFuncAttributeMaxDynamicSharedMemorySize, LDS_BYTES);
  hipFuncSetAttribute(reinterpret_cast<const void*>(&winattn_kernel<false>),
                      hipFuncAttributeMaxDynamicSharedMemorySize, LDS_BYTES);

  prep_weights<<<dim3(288), dim3(512), 0, stream>>>(qkv_w, proj_w, wbf);

  if (ws_size >= (size_t)WS_NEED) {
    float* Y = (float*)((char*)d_ws + WBF_BYTES);
    winattn_kernel<true><<<dim3(4096), dim3(512), LDS_BYTES, stream>>>(
        x, qkv_b, proj_b, rpb, wbf, Y);
    unshift_kernel<<<dim3(1024), dim3(512), 0, stream>>>(Y, out);
  } else {
    winattn_kernel<false><<<dim3(4096), dim3(512), LDS_BYTES, stream>>>(
        x, qkv_b, proj_b, rpb, wbf, out);
  }
}

// Round 4
// 596.967 us; speedup vs baseline: 1.3849x; 1.0907x over previous
//
#include <hip/hip_runtime.h>

// Swin shifted-window attention, fused. B=4, C=192, H=W=256, ws=8, shift=4,
// heads=8, hd=24, N=64. 1 block = 1 window, 512 threads = 8 waves.
// v5: kill the residual ~75 B/thread spill. (a) amdgpu_waves_per_eu(4,4) so
// the allocator budgets 128 VGPR (LDS caps at 2 blocks/CU anyway; v4's
// 64-VGPR occupancy target forced spills). (b) B-fragments (bx/bo) are read
// from LDS inside the kk loop instead of pre-hoisted 96-VGPR arrays.
// (c) unshift epilogue vectorized to 2x float4 per thread.
// v4 carry-over: fully-unrolled mi loop, static indexing everywhere.
// v3 carry-over: window-blocked Y output + unshift epilogue.
// v2 carry-over: LDS diet (81,552 B) for 2 blocks/CU; K->Q->O time-multiplex.
//
// MFMA 16x16x32 bf16 layouts (learn_hip-verified):
//   A-frag: lane holds A[m=lane&15][k=(lane>>4)*8 + j]
//   B-frag: lane holds B[k=(lane>>4)*8 + j][n=lane&15]
//   C/D   : lane holds D[row=(lane>>4)*4 + r][col=lane&15]

typedef short short8 __attribute__((ext_vector_type(8)));
typedef float f32x4 __attribute__((ext_vector_type(4)));
typedef unsigned short us4 __attribute__((ext_vector_type(4)));

// LDS layout (offsets in 16-bit units)
#define XB_OFF   0        // [12288] x bf16, fragment-swizzled; residual source
#define KQ_OFF   12288    // [12288] K (1a) then Q (1b), per-head swz; then O (2b), X-style swz
#define VT_OFF   24576    // [192][72] V channel-major
#define PB_OFF   24576    // P tiles alias V (V is in registers after 2a)
#define RPB_OFF  38400    // bf16 [8][225] rpb head-major
#define QB_OFF   40200    // bf16 qkv_b [576]
#define LDS_BYTES 81552   // 40776 shorts; 2 blocks/CU (2x80KiB granule = 160KiB)

#define WBF_BYTES 294912u
#define Y_FLOATS_PER_WIN 12288        // 192*64
#define Y_BYTES (4096ull * 49152ull)  // 201,326,592
#define WS_NEED (WBF_BYTES + Y_BYTES)

__device__ __forceinline__ unsigned short f2bfu(float f) {
  union { float f; unsigned u; } v; v.f = f;
  unsigned u = v.u;
  u += 0x7fffu + ((u >> 16) & 1u);   // round-to-nearest-even
  return (unsigned short)(u >> 16);
}
__device__ __forceinline__ float bfu2f(unsigned short s) {
  union { unsigned u; float f; } v; v.u = ((unsigned)s) << 16;
  return v.f;
}

// X/O fragment swizzle: element (token t, channel c) -> short index.
// Matches B-frag load *(short8*)(base + ((tt*6+kk)*64 + lane)*8).
__device__ __forceinline__ int swzX(int t, int c) {
  return (((t >> 4) * 6 + (c >> 5)) << 9) | (((c >> 3) & 3) << 7) |
         ((t & 15) << 3) | (c & 7);
}
// K/Q per-head swizzle: (token-tile i, head h, 8-chan group g, token n, chan j)
// holds X[token = i*16+n][chan = h*24 + g*8 + j]
__device__ __forceinline__ int swzH(int i, int h, int g, int n, int j) {
  return (((i * 8 + h) * 3 + g) << 7) | (n << 3) | j;
}

// -------- prologue: qkv_w/proj_w -> bf16, fragment-swizzled into ws --------
__global__ void prep_weights(const float* __restrict__ qkv_w,
                             const float* __restrict__ proj_w,
                             unsigned short* __restrict__ wbf) {
  int d = blockIdx.x * 512 + threadIdx.x;     // 0..147455
  int j    = d & 7;
  int lane = (d >> 3) & 63;
  int kk   = (d >> 9) % 6;
  int tile = d / 3072;
  int n16 = lane & 15, q4 = lane >> 4;
  int col = kk * 32 + q4 * 8 + j;
  float v = (tile < 36) ? qkv_w[(tile * 16 + n16) * 192 + col]
                        : proj_w[((tile - 36) * 16 + n16) * 192 + col];
  wbf[d] = f2bfu(v);
}

template <bool TOY>
__global__ __launch_bounds__(512)
__attribute__((amdgpu_waves_per_eu(4, 4)))
void winattn_kernel(
    const float* __restrict__ x, const float* __restrict__ qkv_b,
    const float* __restrict__ proj_b, const float* __restrict__ rpb,
    const unsigned short* __restrict__ wbf, float* __restrict__ dst)
{
  extern __shared__ __align__(16) char smem[];
  unsigned short* lds = (unsigned short*)smem;

  const int tid  = threadIdx.x;
  const int lane = tid & 63;
  const int wave = tid >> 6;      // 0..7
  const int n16  = lane & 15;
  const int q4   = lane >> 4;

  // XCD-aware swizzle: xcd = blk & 7 heuristic; contiguous window runs per XCD.
  const int blk = blockIdx.x;
  const int L   = (blk & 7) * 512 + (blk >> 3);   // 0..4095 logical
  const int b    = L >> 10;
  const int wIdx = L & 1023;
  const int wr   = wIdx >> 5;
  const int wc   = wIdx & 31;

  // ---------------- phase 0: stage x (bf16, swizzled), rpb, qkv bias ----------------
  {
    const int trow = wave;               // token row 0..7
    const int c3 = lane >> 3, w3 = lane & 7;
    const int hh  = (wr * 8 + 4 + trow) & 255;
    const int ww  = (wc * 8 + 4 + w3) & 255;
    const int t   = trow * 8 + w3;
    #pragma unroll
    for (int it = 0; it < 12; it++) {
      const int c = it * 16 + c3 * 2;
      const float* xp = x + (((size_t)(b * 192 + c)) << 16) + (hh << 8) + ww;
      float v0 = xp[0];
      float v1 = xp[65536];
      unsigned pk = (unsigned)f2bfu(v0) | ((unsigned)f2bfu(v1) << 16);
      *(unsigned*)(lds + XB_OFF + swzX(t, c)) = pk;   // c even -> 4B aligned
    }
    for (int i = tid; i < 1800; i += 512)
      lds[RPB_OFF + (i & 7) * 225 + (i >> 3)] = f2bfu(rpb[i]);  // [h][idx]
    for (int i = tid; i < 576; i += 512)
      lds[QB_OFF + i] = f2bfu(qkv_b[i]);
  }
  __syncthreads();

  // ---------------- phase 1a: K,V = Wkv(384x192) @ X^T (wbf tiles 12..35) ----------------
  {
    #pragma unroll 1
    for (int ot = wave; ot < 24; ot += 8) {
      f32x4 acc[4] = {{0,0,0,0},{0,0,0,0},{0,0,0,0},{0,0,0,0}};
      #pragma unroll
      for (int kk = 0; kk < 6; kk++) {
        short8 af = *(const short8*)(wbf + ((ot + 12) * 6 + kk) * 512 + lane * 8);
        #pragma unroll
        for (int tt = 0; tt < 4; tt++) {
          short8 bxk = *(const short8*)(lds + XB_OFF + ((tt * 6 + kk) * 64 + lane) * 8);
          acc[tt] = __builtin_amdgcn_mfma_f32_16x16x32_bf16(af, bxk, acc[tt], 0, 0, 0);
        }
      }
      const int ob = (ot + 12) * 16 + q4 * 4;
      const float b0 = bfu2f(lds[QB_OFF + ob + 0]);
      const float b1 = bfu2f(lds[QB_OFF + ob + 1]);
      const float b2 = bfu2f(lds[QB_OFF + ob + 2]);
      const float b3 = bfu2f(lds[QB_OFF + ob + 3]);
      if (ot < 12) {
        const int kc = ot * 16 + q4 * 4;
        const int hk = kc / 24, g = (kc >> 3) % 3, j0 = kc & 7;
        #pragma unroll
        for (int tt = 0; tt < 4; tt++) {
          us4 hv = { f2bfu(acc[tt][0] + b0), f2bfu(acc[tt][1] + b1),
                     f2bfu(acc[tt][2] + b2), f2bfu(acc[tt][3] + b3) };
          *(us4*)(lds + KQ_OFF + swzH(tt, hk, g, n16, j0)) = hv;
        }
      } else {
        const int vc = (ot - 12) * 16 + q4 * 4;
        #pragma unroll
        for (int tt = 0; tt < 4; tt++) {
          const int t = tt * 16 + n16;
          lds[VT_OFF + (vc + 0) * 72 + t] = f2bfu(acc[tt][0] + b0);
          lds[VT_OFF + (vc + 1) * 72 + t] = f2bfu(acc[tt][1] + b1);
          lds[VT_OFF + (vc + 2) * 72 + t] = f2bfu(acc[tt][2] + b2);
          lds[VT_OFF + (vc + 3) * 72 + t] = f2bfu(acc[tt][3] + b3);
        }
      }
    }
  }
  __syncthreads();

  // ---------------- phase 2a: snapshot K/V fragments (wave = head) ----------------
  const int h = wave;
  const short8 zero8 = {0,0,0,0,0,0,0,0};
  short8 kb[4], vb[2][2];
  {
    #pragma unroll
    for (int i = 0; i < 4; i++)
      kb[i] = (q4 < 3) ? *(const short8*)(lds + KQ_OFF + swzH(i, h, q4, n16, 0))
                       : zero8;
    #pragma unroll
    for (int nc = 0; nc < 2; nc++)
      #pragma unroll
      for (int kk = 0; kk < 2; kk++)
        vb[nc][kk] = (nc * 16 + n16 < 24)
          ? *(const short8*)(lds + VT_OFF + (h * 24 + nc * 16 + n16) * 72 + kk * 32 + q4 * 8)
          : zero8;
  }
  __syncthreads();   // all K/V reads done; KQ region free for Q

  // ---------------- phase 1b: Q = Wq(192x192) @ X^T (wbf tiles 0..11) ----------------
  {
    #pragma unroll 1
    for (int ot = wave; ot < 12; ot += 8) {
      f32x4 acc[4] = {{0,0,0,0},{0,0,0,0},{0,0,0,0},{0,0,0,0}};
      #pragma unroll
      for (int kk = 0; kk < 6; kk++) {
        short8 af = *(const short8*)(wbf + (ot * 6 + kk) * 512 + lane * 8);
        #pragma unroll
        for (int tt = 0; tt < 4; tt++) {
          short8 bxk = *(const short8*)(lds + XB_OFF + ((tt * 6 + kk) * 64 + lane) * 8);
          acc[tt] = __builtin_amdgcn_mfma_f32_16x16x32_bf16(af, bxk, acc[tt], 0, 0, 0);
        }
      }
      const int ob = ot * 16 + q4 * 4;
      const float b0 = bfu2f(lds[QB_OFF + ob + 0]);
      const float b1 = bfu2f(lds[QB_OFF + ob + 1]);
      const float b2 = bfu2f(lds[QB_OFF + ob + 2]);
      const float b3 = bfu2f(lds[QB_OFF + ob + 3]);
      const int qc = ot * 16 + q4 * 4;
      const int hq = qc / 24, g = (qc >> 3) % 3, j0 = qc & 7;
      #pragma unroll
      for (int tt = 0; tt < 4; tt++) {
        us4 hv = { f2bfu(acc[tt][0] + b0), f2bfu(acc[tt][1] + b1),
                   f2bfu(acc[tt][2] + b2), f2bfu(acc[tt][3] + b3) };
        *(us4*)(lds + KQ_OFF + swzH(tt, hq, g, n16, j0)) = hv;
      }
    }
  }
  __syncthreads();

  // ---------------- phase 2: Q frags; fused per-row-tile QK^T + softmax + PV ----------------
  {
    short8 qa[4];
    #pragma unroll
    for (int i = 0; i < 4; i++)
      qa[i] = (q4 < 3) ? *(const short8*)(lds + KQ_OFF + swzH(i, h, q4, n16, 0))
                       : zero8;
    __syncthreads();   // all Q reads done; KQ region free for O

    const float scale = 0.20412414523193154f;   // 24^-0.5
    unsigned short* Pw = lds + PB_OFF + wave * 1152;   // [16][72], aliases V
    const unsigned short* rh = lds + RPB_OFF + h * 225;
    int cr[4], cc[4], clab[4];
    #pragma unroll
    for (int nj = 0; nj < 4; nj++) {
      int col = nj * 16 + n16;
      cr[nj] = col >> 3; cc[nj] = col & 7;
      int hs = wr * 8 + cr[nj], wsc = wc * 8 + cc[nj];
      int lh = (hs < 248) ? 0 : (hs < 252 ? 1 : 2);
      int lw = (wsc < 248) ? 0 : (wsc < 252 ? 1 : 2);
      clab[nj] = lh * 3 + lw;
    }
    // FULLY unrolled: every index into qa/smi/vals is compile-time constant
    // (rule #20 — runtime-indexed ext_vector arrays go to scratch).
    #pragma unroll
    for (int mi = 0; mi < 4; mi++) {
      f32x4 smi[4];
      #pragma unroll
      for (int nj = 0; nj < 4; nj++) {
        f32x4 z = {0,0,0,0};
        smi[nj] = __builtin_amdgcn_mfma_f32_16x16x32_bf16(qa[mi], kb[nj], z, 0, 0, 0);
      }
      #pragma unroll
      for (int r = 0; r < 4; r++) {
        int row = mi * 16 + q4 * 4 + r;
        int r1 = row >> 3, c1 = row & 7;
        int hs = wr * 8 + r1, wsc = wc * 8 + c1;
        int lh = (hs < 248) ? 0 : (hs < 252 ? 1 : 2);
        int lw = (wsc < 248) ? 0 : (wsc < 252 ? 1 : 2);
        int rlab = lh * 3 + lw;
        float vals[4];
        float mx = -1e30f;
        #pragma unroll
        for (int nj = 0; nj < 4; nj++) {
          float v = smi[nj][r] * scale
                  + bfu2f(rh[(r1 - cr[nj] + 7) * 15 + (c1 - cc[nj] + 7)])
                  + ((rlab == clab[nj]) ? 0.0f : -100.0f);
          vals[nj] = v;
          mx = fmaxf(mx, v);
        }
        mx = fmaxf(mx, __shfl_xor(mx, 1));
        mx = fmaxf(mx, __shfl_xor(mx, 2));
        mx = fmaxf(mx, __shfl_xor(mx, 4));
        mx = fmaxf(mx, __shfl_xor(mx, 8));
        float sum = 0.f;
        #pragma unroll
        for (int nj = 0; nj < 4; nj++) { float p = __expf(vals[nj] - mx); vals[nj] = p; sum += p; }
        sum += __shfl_xor(sum, 1);
        sum += __shfl_xor(sum, 2);
        sum += __shfl_xor(sum, 4);
        sum += __shfl_xor(sum, 8);
        float inv = 1.0f / sum;
        #pragma unroll
        for (int nj = 0; nj < 4; nj++)
          Pw[(q4 * 4 + r) * 72 + nj * 16 + n16] = f2bfu(vals[nj] * inv);
      }
      short8 pa0 = *(const short8*)(Pw + n16 * 72 + q4 * 8);
      short8 pa1 = *(const short8*)(Pw + n16 * 72 + 32 + q4 * 8);
      #pragma unroll
      for (int nc = 0; nc < 2; nc++) {
        f32x4 a = {0,0,0,0};
        a = __builtin_amdgcn_mfma_f32_16x16x32_bf16(pa0, vb[nc][0], a, 0, 0, 0);
        a = __builtin_amdgcn_mfma_f32_16x16x32_bf16(pa1, vb[nc][1], a, 0, 0, 0);
        const int ch = nc * 16 + n16;
        if (ch < 24) {
          const int c = h * 24 + ch;
          #pragma unroll
          for (int r = 0; r < 4; r++) {
            const int t = mi * 16 + q4 * 4 + r;
            lds[KQ_OFF + swzX(t, c)] = f2bfu(a[r]);   // O, X-style swz
          }
        }
      }
    }
  }
  __syncthreads();

  // ---------------- phase 3: proj^T = Wp(192x192) @ O^T, + residual ----------------
  {
    #pragma unroll 1
    for (int ot = wave; ot < 12; ot += 8) {
      f32x4 acc[4] = {{0,0,0,0},{0,0,0,0},{0,0,0,0},{0,0,0,0}};
      #pragma unroll
      for (int kk = 0; kk < 6; kk++) {
        short8 af = *(const short8*)(wbf + ((36 + ot) * 6 + kk) * 512 + lane * 8);
        #pragma unroll
        for (int tt = 0; tt < 4; tt++) {
          short8 bok = *(const short8*)(lds + KQ_OFF + ((tt * 6 + kk) * 64 + lane) * 8);
          acc[tt] = __builtin_amdgcn_mfma_f32_16x16x32_bf16(af, bok, acc[tt], 0, 0, 0);
        }
      }
      if constexpr (TOY) {
        // contiguous window-blocked store: Y[win][o][t], full 64B lines
        float* yw = dst + (size_t)L * Y_FLOATS_PER_WIN;
        #pragma unroll
        for (int r = 0; r < 4; r++) {
          const int o = ot * 16 + q4 * 4 + r;
          const float pb = proj_b[o];
          #pragma unroll
          for (int tt = 0; tt < 4; tt++) {
            const int t = tt * 16 + n16;
            yw[o * 64 + t] = bfu2f(lds[XB_OFF + swzX(t, o)]) + acc[tt][r] + pb;
          }
        }
      } else {
        #pragma unroll
        for (int r = 0; r < 4; r++) {
          const int o = ot * 16 + q4 * 4 + r;
          const float pb = proj_b[o];
          const size_t cbase = ((size_t)(b * 192 + o)) << 16;
          #pragma unroll
          for (int tt = 0; tt < 4; tt++) {
            const int t = tt * 16 + n16;
            const int hh = (wr * 8 + (t >> 3) + 4) & 255;
            const int ww = (wc * 8 + (t & 7) + 4) & 255;
            dst[cbase + (hh << 8) + ww] = bfu2f(lds[XB_OFF + swzX(t, o)]) + acc[tt][r] + pb;
          }
        }
      }
    }
  }
}

// -------- epilogue: Y[win][c][t] (window-blocked, shifted space) -> out(B,C,H,W) --------
// out(c, h, w) = Y[win(b, (h-4)>>3, (w-4)>>3)][c][((h-4)&7)*8 + ((w-4)&7)]
// Block = (b, wr, cg of 24 channels). Vectorized: each thread moves one
// window-row segment of 8 floats as 2x float4 (16B-aligned both sides; the
// rotation-by-4 keeps float4 boundaries). Writes are contiguous per out-row.
__global__ __launch_bounds__(512) void unshift_kernel(
    const float* __restrict__ Y, float* __restrict__ out)
{
  const int bid = blockIdx.x;
  const int cg = bid & 7;           // 8 channel groups x 24
  const int wr = (bid >> 3) & 31;
  const int b  = bid >> 8;
  const size_t winrow = ((size_t)(b * 32 + wr)) * 32;   // first window of this row-band

  #pragma unroll
  for (int it = 0; it < 12; it++) {
    const int i = it * 512 + threadIdx.x;   // 0..6143
    const int c_rel = i >> 8;               // 0..23
    const int rem   = i & 255;
    const int trow  = rem >> 5;             // 0..7
    const int k     = rem & 31;             // window column
    const int c     = cg * 24 + c_rel;
    const float* src = Y + (winrow + k) * Y_FLOATS_PER_WIN + c * 64 + trow * 8;
    f32x4 v0 = *(const f32x4*)(src);
    f32x4 v1 = *(const f32x4*)(src + 4);
    const int hh = (wr * 8 + trow + 4) & 255;
    float* drow = out + (((size_t)(b * 192 + c)) << 16) + (hh << 8);
    *(f32x4*)(drow + ((k * 8 + 4) & 255)) = v0;
    *(f32x4*)(drow + ((k * 8 + 8) & 255)) = v1;
  }
}

extern "C" void kernel_launch(void* const* d_in, const int* in_sizes, int n_in,
                              void* d_out, int out_size, void* d_ws, size_t ws_size,
                              hipStream_t stream) {
  const float* x      = (const float*)d_in[0];
  const float* qkv_w  = (const float*)d_in[1];
  const float* qkv_b  = (const float*)d_in[2];
  const float* proj_w = (const float*)d_in[3];
  const float* proj_b = (const float*)d_in[4];
  const float* rpb    = (const float*)d_in[5];
  float* out = (float*)d_out;
  unsigned short* wbf = (unsigned short*)d_ws;    // 147456 shorts = 294912 B

  hipFuncSetAttribute(reinterpret_cast<const void*>(&winattn_kernel<true>),
                      hipFuncAttributeMaxDynamicSharedMemorySize, LDS_BYTES);
  hipFuncSetAttribute(reinterpret_cast<const void*>(&winattn_kernel<false>),
                      hipFuncAttributeMaxDynamicSharedMemorySize, LDS_BYTES);

  prep_weights<<<dim3(288), dim3(512), 0, stream>>>(qkv_w, proj_w, wbf);

  if (ws_size >= (size_t)WS_NEED) {
    float* Y = (float*)((char*)d_ws + WBF_BYTES);
    winattn_kernel<true><<<dim3(4096), dim3(512), LDS_BYTES, stream>>>(
        x, qkv_b, proj_b, rpb, wbf, Y);
    unshift_kernel<<<dim3(1024), dim3(512), 0, stream>>>(Y, out);
  } else {
    winattn_kernel<false><<<dim3(4096), dim3(512), LDS_BYTES, stream>>>(
        x, qkv_b, proj_b, rpb, wbf, out);
  }
}